// Round 4
// baseline (354.242 us; speedup 1.0000x reference)
//
#include <hip/hip_runtime.h>
#include <hip/hip_bf16.h>

typedef __attribute__((ext_vector_type(4))) float  f32x4;
typedef __attribute__((ext_vector_type(8))) short  s16x8;
typedef __attribute__((ext_vector_type(4))) short  s16x4;

union BH4 { s16x4 v; __hip_bfloat16 h[4]; };
union BH8 { s16x8 v; __hip_bfloat16 h[8]; };

#define MFMA16(A,B,C) __builtin_amdgcn_mfma_f32_16x16x32_bf16((A),(B),(C),0,0,0)

__device__ __forceinline__ float sigm(float x) { return 1.0f / (1.0f + __expf(-x)); }

// [rows][256] bf16 (512 B rows): XOR row into 16B slot (bank-conflict fix)
__device__ __forceinline__ int xad(int r, int byteInRow) {
  return ((r << 9) + byteInRow) ^ ((r & 7) << 4);
}
// chunk buffers: [rows][64] bf16 (128 B rows): slot16 ^= (i&7)
__device__ __forceinline__ int cad64(int i, int k) {   // k = bf16 idx 0..63
  return (i << 7) + ((((k >> 3) ^ (i & 7)) << 4) | ((k & 7) << 1));
}

// fp32 weight [256][256] -> bf16 MFMA B-fragment order:
// dst[((ct*8+ks)*64+lane)*8 + j] = w[ct*16 + (lane&15)][ks*32 + (lane>>4)*8 + j]
__global__ void wfrag_kernel(const float* __restrict__ w_in,
                             const float* __restrict__ w_gate,
                             const float* __restrict__ w_out,
                             __hip_bfloat16* __restrict__ dst) {
  const int lane = threadIdx.x;         // 64
  const int fid  = blockIdx.x;          // 0..127 = ct*8+ks
  const int m    = blockIdx.y;          // 0:wa 1:wb 2:wg 3:wo
  const float* src = (m == 0) ? w_in : (m == 1) ? (w_in + 65536)
                    : (m == 2) ? w_gate : w_out;
  const int e  = (fid >> 3) * 16 + (lane & 15);
  const int d0 = (fid & 7) * 32 + (lane >> 4) * 8;
  BH8 u;
  #pragma unroll
  for (int j = 0; j < 8; ++j) u.h[j] = __float2bfloat16(src[e * 256 + d0 + j]);
  *reinterpret_cast<s16x8*>(dst + (size_t)m * 65536 + ((size_t)fid * 64 + lane) * 8) = u.v;
}

// K1: x = LN(pair) -> xws in A-fragment order:
// xws[((s*16+rt)*8+ks)*512 + lane*8 + j] = x[s][rt*16 + (lane&15)][ks*32 + (lane>>4)*8 + j]
__global__ __launch_bounds__(256) void ln_kernel(
    const float* __restrict__ pair, const float* __restrict__ gamma,
    const float* __restrict__ beta, __hip_bfloat16* __restrict__ xws)
{
  __shared__ char Xl[8192];
  const int t  = threadIdx.x;
  const int s  = blockIdx.x >> 4;
  const int rt = blockIdx.x & 15;
  const int r  = t >> 4;                 // local row 0..15
  const int c0 = (t & 15) * 16;
  const float* src = pair + (((size_t)s * 256 + rt * 16 + r) * 256 + c0);
  float v[16];
  #pragma unroll
  for (int i = 0; i < 4; ++i) {
    const float4 f = *reinterpret_cast<const float4*>(src + i * 4);
    v[i*4+0]=f.x; v[i*4+1]=f.y; v[i*4+2]=f.z; v[i*4+3]=f.w;
  }
  float sm = 0.f, ss = 0.f;
  #pragma unroll
  for (int i = 0; i < 16; ++i) { sm += v[i]; ss += v[i]*v[i]; }
  #pragma unroll
  for (int m = 1; m < 16; m <<= 1) { sm += __shfl_xor(sm, m); ss += __shfl_xor(ss, m); }
  const float mean = sm * (1.f/256.f);
  const float rstd = rsqrtf(ss * (1.f/256.f) - mean*mean + 1e-5f);
  #pragma unroll
  for (int i = 0; i < 4; ++i) {
    const float4 gm = *reinterpret_cast<const float4*>(gamma + c0 + i*4);
    const float4 bt = *reinterpret_cast<const float4*>(beta  + c0 + i*4);
    BH4 o;
    o.h[0] = __float2bfloat16((v[i*4+0]-mean)*rstd*gm.x + bt.x);
    o.h[1] = __float2bfloat16((v[i*4+1]-mean)*rstd*gm.y + bt.y);
    o.h[2] = __float2bfloat16((v[i*4+2]-mean)*rstd*gm.z + bt.z);
    o.h[3] = __float2bfloat16((v[i*4+3]-mean)*rstd*gm.w + bt.w);
    *reinterpret_cast<s16x4*>(Xl + xad(r, (c0 + i*4)*2)) = o.v;
  }
  __syncthreads();
  #pragma unroll
  for (int p = 0; p < 2; ++p) {
    const int u  = t + p * 256;
    const int ks = u >> 6;
    const int lp = u & 63;
    const s16x8 f = *reinterpret_cast<const s16x8*>(
        Xl + xad(lp & 15, ks*64 + ((lp>>4)&3)*16));
    *reinterpret_cast<s16x8*>(xws + ((((size_t)s*16 + rt)*8 + ks)*64 + lp)*8) = f;
  }
}

// K2: block = half-slice (128 tri rows). 8 waves, 512 thr, 64 KB LDS, <=128 VGPR.
// A-fragments of x are read directly from L2 (no LDS staging).
__global__ __launch_bounds__(512, 2) void tri_fused(
    const __hip_bfloat16* __restrict__ xws,
    const __hip_bfloat16* __restrict__ wfrag,
    const float* __restrict__ gamma, const float* __restrict__ beta,
    float* __restrict__ out)
{
  __shared__ __align__(16) char lds[65536];
  char* const AC = lds;            // 16384 B : a^T chunk [128 i][64 k] swz
  char* const BC = lds + 16384;    // 32768 B : b^T chunk [256 j][64 k] swz
  char* const SW = lds;            // 65536 B : ln(tri) [128 i][256 j] bf16 (reuse)

  const int raw = blockIdx.x;                 // 1024 blocks
  const int xcd = raw & 7, o = raw >> 3;
  const int s   = xcd * 64 + (o >> 1);        // slice 0..511 (siblings same XCD)
  const int h   = o & 1;                      // half: tri rows h*128..h*128+127

  const int tid = threadIdx.x, lane = tid & 63, w = tid >> 6;   // 8 waves
  const int l15 = lane & 15, lh = lane >> 4;                    // lh 0..3

  const __hip_bfloat16* const wa = wfrag;
  const __hip_bfloat16* const wb = wfrag + 65536;
  const __hip_bfloat16* const wg = wfrag + 131072;
  const __hip_bfloat16* const wo = wfrag + 196608;
  const __hip_bfloat16* const xs = xws + (size_t)s * 65536;

  f32x4 tri[16];
  #pragma unroll
  for (int jt = 0; jt < 16; ++jt) tri[jt] = (f32x4){0.f,0.f,0.f,0.f};

  for (int c = 0; c < 4; ++c) {
    // ---- phase A: a-GEMM, this wave's a col-tile (global ct = h*8+w)
    {
      const int ct = h*8 + w;
      f32x4 acc[4];
      #pragma unroll
      for (int rt = 0; rt < 4; ++rt) acc[rt] = (f32x4){0.f,0.f,0.f,0.f};
      #pragma unroll
      for (int ks = 0; ks < 8; ++ks) {
        const s16x8 Bf = *reinterpret_cast<const s16x8*>(wa + (((size_t)ct*8 + ks)*64 + lane)*8);
        #pragma unroll
        for (int rt = 0; rt < 4; ++rt) {
          const s16x8 Af = *reinterpret_cast<const s16x8*>(
              xs + (((size_t)(c*4 + rt)*8 + ks)*64 + lane)*8);
          acc[rt] = MFMA16(Af, Bf, acc[rt]);
        }
      }
      #pragma unroll
      for (int rt = 0; rt < 4; ++rt) {
        const f32x4 vv = acc[rt];
        BH4 ov;
        #pragma unroll
        for (int q = 0; q < 4; ++q) ov.h[q] = __float2bfloat16(vv[q] * sigm(vv[q]));
        *reinterpret_cast<s16x4*>(AC + cad64(w*16 + l15, rt*16 + lh*4)) = ov.v;
      }
    }
    // ---- phases B0,B1: b-GEMM for ct = 2w, 2w+1 (16 col-tiles over 8 waves)
    #pragma unroll
    for (int t = 0; t < 2; ++t) {
      const int ct = 2*w + t;
      f32x4 acc[4];
      #pragma unroll
      for (int rt = 0; rt < 4; ++rt) acc[rt] = (f32x4){0.f,0.f,0.f,0.f};
      #pragma unroll
      for (int ks = 0; ks < 8; ++ks) {
        const s16x8 Bf = *reinterpret_cast<const s16x8*>(wb + (((size_t)ct*8 + ks)*64 + lane)*8);
        #pragma unroll
        for (int rt = 0; rt < 4; ++rt) {
          const s16x8 Af = *reinterpret_cast<const s16x8*>(
              xs + (((size_t)(c*4 + rt)*8 + ks)*64 + lane)*8);
          acc[rt] = MFMA16(Af, Bf, acc[rt]);
        }
      }
      #pragma unroll
      for (int rt = 0; rt < 4; ++rt) {
        const f32x4 vv = acc[rt];
        BH4 ov;
        #pragma unroll
        for (int q = 0; q < 4; ++q) ov.h[q] = __float2bfloat16(vv[q] * sigm(vv[q]));
        *reinterpret_cast<s16x4*>(BC + cad64(ct*16 + l15, rt*16 + lh*4)) = ov.v;
      }
    }
    __syncthreads();   // chunk bufs ready (and prior tri reads done via loop-end barrier)

    // ---- tri accumulation: tri[i][j] += sum_k aT[i][k] bT[j][k]  (K=64)
    #pragma unroll
    for (int kss = 0; kss < 2; ++kss) {
      const s16x8 ta = *reinterpret_cast<const s16x8*>(AC + cad64(w*16 + l15, kss*32 + lh*8));
      #pragma unroll
      for (int jt = 0; jt < 16; ++jt) {
        const s16x8 tb = *reinterpret_cast<const s16x8*>(BC + cad64(jt*16 + l15, kss*32 + lh*8));
        tri[jt] = MFMA16(ta, tb, tri[jt]);
      }
    }
    __syncthreads();   // tri reads done before next chunk overwrites AC/BC
  }

  // ---- LN(tri) in-wave; stage ln(tri) bf16 into SW (overlays chunk bufs)
  {
    float mean[4], rstd[4];
    #pragma unroll
    for (int q = 0; q < 4; ++q) {
      float sm = 0.f, ss = 0.f;
      #pragma unroll
      for (int jt = 0; jt < 16; ++jt) { const float x = tri[jt][q]; sm += x; ss += x*x; }
      #pragma unroll
      for (int m = 1; m < 16; m <<= 1) { sm += __shfl_xor(sm, m); ss += __shfl_xor(ss, m); }
      mean[q] = sm * (1.f/256.f);
      rstd[q] = rsqrtf(ss * (1.f/256.f) - mean[q]*mean[q] + 1e-5f);
    }
    #pragma unroll
    for (int jt = 0; jt < 16; ++jt) {
      const float gm = gamma[jt*16 + l15];
      const float bt = beta [jt*16 + l15];
      #pragma unroll
      for (int q = 0; q < 4; ++q) {
        const float vv = (tri[jt][q] - mean[q]) * rstd[q] * gm + bt;
        *reinterpret_cast<__hip_bfloat16*>(
            SW + xad(w*16 + lh*4 + q, (jt*16 + l15)*2)) = __float2bfloat16(vv);
      }
    }
  }
  __syncthreads();

  // ---- out = (LN(tri) @ Wo^T) * sigmoid(x @ Wg^T); wave owns cols ct=2w,2w+1
  #pragma unroll
  for (int half = 0; half < 2; ++half) {
    #pragma unroll
    for (int t = 0; t < 2; ++t) {
      const int ct = 2*w + t;
      f32x4 og[4], oo[4];
      #pragma unroll
      for (int rt = 0; rt < 4; ++rt) { og[rt] = (f32x4){0.f,0.f,0.f,0.f}; oo[rt] = (f32x4){0.f,0.f,0.f,0.f}; }
      #pragma unroll
      for (int ks = 0; ks < 8; ++ks) {
        const s16x8 Bg = *reinterpret_cast<const s16x8*>(wg + (((size_t)ct*8 + ks)*64 + lane)*8);
        const s16x8 Bo = *reinterpret_cast<const s16x8*>(wo + (((size_t)ct*8 + ks)*64 + lane)*8);
        #pragma unroll
        for (int rt = 0; rt < 4; ++rt) {
          const int rtg = h*8 + half*4 + rt;   // global x row-tile
          const s16x8 Ax  = *reinterpret_cast<const s16x8*>(xs + (((size_t)rtg*8 + ks)*64 + lane)*8);
          const s16x8 Aln = *reinterpret_cast<const s16x8*>(
              SW + xad(half*64 + rt*16 + l15, ks*64 + lh*16));
          og[rt] = MFMA16(Ax,  Bg, og[rt]);
          oo[rt] = MFMA16(Aln, Bo, oo[rt]);
        }
      }
      #pragma unroll
      for (int rt = 0; rt < 4; ++rt) {
        #pragma unroll
        for (int q = 0; q < 4; ++q) {
          const int row = h*128 + half*64 + rt*16 + lh*4 + q;
          out[(size_t)s*65536 + (size_t)row*256 + ct*16 + l15] =
              oo[rt][q] * sigm(og[rt][q]);
        }
      }
    }
  }
}

extern "C" void kernel_launch(void* const* d_in, const int* in_sizes, int n_in,
                              void* d_out, int out_size, void* d_ws, size_t ws_size,
                              hipStream_t stream) {
  const float* pair   = (const float*)d_in[0];
  const float* w_in   = (const float*)d_in[1];
  const float* w_gate = (const float*)d_in[2];
  const float* w_out  = (const float*)d_in[3];
  const float* gamma  = (const float*)d_in[4];
  const float* beta   = (const float*)d_in[5];
  float* out = (float*)d_out;

  __hip_bfloat16* wfrag = (__hip_bfloat16*)d_ws;                    // 512 KB
  __hip_bfloat16* xws   = (__hip_bfloat16*)((char*)d_ws + 524288);  // 67 MB

  (void)in_sizes; (void)n_in; (void)out_size; (void)ws_size;

  wfrag_kernel<<<dim3(128, 4), 64, 0, stream>>>(w_in, w_gate, w_out, wfrag);
  ln_kernel<<<8192, 256, 0, stream>>>(pair, gamma, beta, xws);
  tri_fused<<<1024, 512, 0, stream>>>(xws, wfrag, gamma, beta, out);
}